// Round 1
// baseline (75.872 us; speedup 1.0000x reference)
//
#include <hip/hip_runtime.h>
#include <hip/hip_fp16.h>
#include <math.h>
#include <stdint.h>

#define B_SZ 64
#define P_SZ 256
#define N_SZ 4096
#define A_ANC 0.08f
#define OMEGA_ANC 1256.6370614359172f
#define INV_2PI 0.15915494309189535f

typedef _Float16 half8 __attribute__((ext_vector_type(8)));
typedef float floatx4 __attribute__((ext_vector_type(4)));

// raw v_sin/v_cos: D = sin(2*pi*r). Inputs pre-scaled by 1/2pi (args in [0,2pi)).
__device__ __forceinline__ float vsin_r(float r) {
#if __has_builtin(__builtin_amdgcn_sinf)
    return __builtin_amdgcn_sinf(r);
#else
    return __sinf(r * 6.283185307179586f);
#endif
}
__device__ __forceinline__ float vcos_r(float r) {
#if __has_builtin(__builtin_amdgcn_cosf)
    return __builtin_amdgcn_cosf(r);
#else
    return __cosf(r * 6.283185307179586f);
#endif
}
__device__ __forceinline__ float vfract(float r) {
#if __has_builtin(__builtin_amdgcn_fractf)
    return __builtin_amdgcn_fractf(r);
#else
    return r - floorf(r);
#endif
}
// {cos(x), sin(x)} packed to half2 dword in one v_cvt_pkrtz
__device__ __forceinline__ uint32_t cs_pack(float x) {
    float r = x * INV_2PI;
    return __builtin_bit_cast(uint32_t,
        __builtin_amdgcn_cvt_pkrtz(vcos_r(r), vsin_r(r)));
}

__device__ __forceinline__ uint32_t permsel(uint32_t hi, uint32_t lo, uint32_t sel) {
#if __has_builtin(__builtin_amdgcn_perm)
    return __builtin_amdgcn_perm(hi, lo, sel);
#else
    unsigned long long v = ((unsigned long long)hi << 32) | lo;
    uint32_t r = 0;
#pragma unroll
    for (int i = 0; i < 4; ++i)
        r |= (uint32_t)((v >> (8 * ((sel >> (8 * i)) & 7))) & 0xff) << (8 * i);
    return r;
#endif
}

// K1: m-GEMM via MFMA (R5-R9 verified math). Partial sums go straight into
// m_total[b][p] via atomicAdd (m_total pre-zeroed by a memset node) -- this
// deletes the k_weights kernel + m_part round trip entirely.
// bt==0 waves store B-frags to XPT[n][p] ({cos,sin} half2 dword), each (n,p) once.
// grid (64, 8) x 4 waves = 2048 waves = 8/CU. No LDS, no barriers.
__global__ __launch_bounds__(256) void k_mpart_mfma(const float* __restrict__ phi,
                                                    const float* __restrict__ xi,
                                                    uint32_t* __restrict__ XPT,
                                                    float* __restrict__ m_total) {
    const int bt = blockIdx.x & 3;          // b-tile (4 x 16)
    const int pt = blockIdx.x >> 2;         // p-tile (16 x 16)
    const int w  = threadIdx.x >> 6;
    const int lane = threadIdx.x & 63;
    const int m = lane & 15;
    const int q = lane >> 4;

    const int c  = blockIdx.y * 4 + w;      // K chunk 0..31 (128 n each)
    const int n0 = c * 128;
    const int b_row = bt * 16 + m;
    const int p_row = pt * 16 + m;

    floatx4 acc = {0.f, 0.f, 0.f, 0.f};
#pragma unroll
    for (int s = 0; s < 8; ++s) {
        const int nb = n0 + s * 16 + q * 4;                    // this lane's 4 n's
        float4 ph = *(const float4*)&phi[b_row * N_SZ + nb];   // A source (line-dense)
        float4 xv = *(const float4*)&xi[p_row * N_SZ + nb];    // B source (line-dense)
        uint4 ai, bi;
        ai.x = cs_pack(ph.x); ai.y = cs_pack(ph.y);
        ai.z = cs_pack(ph.z); ai.w = cs_pack(ph.w);
        bi.x = cs_pack(xv.x); bi.y = cs_pack(xv.y);
        bi.z = cs_pack(xv.z); bi.w = cs_pack(xv.w);
        if (bt == 0) {                                         // wave-uniform branch
            XPT[(nb + 0) * P_SZ + p_row] = bi.x;
            XPT[(nb + 1) * P_SZ + p_row] = bi.y;
            XPT[(nb + 2) * P_SZ + p_row] = bi.z;
            XPT[(nb + 3) * P_SZ + p_row] = bi.w;
        }
        half8 af = __builtin_bit_cast(half8, ai);
        half8 bf = __builtin_bit_cast(half8, bi);
        acc = __builtin_amdgcn_mfma_f32_16x16x32_f16(af, bf, acc, 0, 0, 0);
    }
    // D: col(p)=lane&15, row(b)=q*4+r [verified]; accumulate across chunks
#pragma unroll
    for (int r = 0; r < 4; ++r) {
        int b = bt * 16 + q * 4 + r;
        atomicAdd(&m_total[b * 256 + pt * 16 + m], acc[r]);
    }
}

// K2: in-block softmax + coupling MFMA + anchor (R6-R9 verified math).
// Softmax: wave w computes weight rows bl=w*4..w*4+3 for this block's mt from
// m_total (dwordx4 + 6-step shfl reductions, no barriers) into LDS f16 table.
// B staged through LDS row-dense (R8). One __syncthreads covers both.
// grid (4 mt, 128 ctg) = 512 blocks, ~41KB LDS, 8 waves/CU.
__global__ __launch_bounds__(256) void k_coupling_mfma(const uint32_t* __restrict__ XPT,
                                                       const float* __restrict__ m_total,
                                                       const float* __restrict__ phi,
                                                       const float* __restrict__ t_ptr,
                                                       float* __restrict__ out) {
    const int mt = blockIdx.x;                             // 0..3
    const int ctg = blockIdx.y;                            // 0..127
    const int tid = threadIdx.x;
    const int w = tid >> 6;
    const int lane = tid & 63;
    const int cl = lane & 15;
    const int q  = lane >> 4;

    __shared__ uint32_t xs[32][260];                       // 32 XPT rows + pad
    __shared__ _Float16 wh[16][264];                       // weight rows + pad

    const int n0 = ctg * 32;
#pragma unroll
    for (int it = 0; it < 8; ++it) {
        int i = tid + it * 256;
        int row = i >> 6, seg = i & 63;
        uint4 v = *(const uint4*)&XPT[(n0 + row) * P_SZ + seg * 4];
        *(uint4*)&xs[row][seg * 4] = v;
    }

    // softmax for this block's 16 b-rows; wave w owns bl = w*4..w*4+3
#pragma unroll
    for (int j = 0; j < 4; ++j) {
        const int bl = w * 4 + j;
        float4 v = *(const float4*)&m_total[(mt * 16 + bl) * 256 + lane * 4];
        float4 l = {v.x * (1.0f / 4096.0f), v.y * (1.0f / 4096.0f),
                    v.z * (1.0f / 4096.0f), v.w * (1.0f / 4096.0f)};
        float mx = fmaxf(fmaxf(l.x, l.y), fmaxf(l.z, l.w));
        for (int o = 32; o > 0; o >>= 1) mx = fmaxf(mx, __shfl_xor(mx, o));
        float e0 = __expf(l.x - mx), e1 = __expf(l.y - mx);
        float e2 = __expf(l.z - mx), e3 = __expf(l.w - mx);
        float s = e0 + e1 + e2 + e3;
        for (int o = 32; o > 0; o >>= 1) s += __shfl_xor(s, o);
        float rs = 1.0f / s;
        uint2 pk;
        pk.x = __builtin_bit_cast(uint32_t,
                 __builtin_amdgcn_cvt_pkrtz(e0 * rs, e1 * rs));
        pk.y = __builtin_bit_cast(uint32_t,
                 __builtin_amdgcn_cvt_pkrtz(e2 * rs, e3 * rs));
        *(uint2*)&wh[bl][lane * 4] = pk;                   // 8B ds_write
    }
    __syncthreads();

    const int ct  = ctg * 4 + w;
    const int col = ct * 16 + cl;                          // 0..8191
    const int n   = col >> 1;
    const int n_l = w * 8 + (cl >> 1);                     // n - n0
    const int comp = col & 1;                              // 0=cos(lo), 1=sin(hi)
    const uint32_t sel = comp ? 0x07060302u : 0x05040100u;

    floatx4 acc = {0.f, 0.f, 0.f, 0.f};
#pragma unroll
    for (int s = 0; s < 8; ++s) {
        const int k0 = s * 32 + q * 8;                     // this lane's first p
        half8 af = *(const half8*)&wh[cl][k0];             // LDS weight frag
        uint4 v0 = *(const uint4*)&xs[n_l][k0];            // ds_read_b128
        uint4 v1 = *(const uint4*)&xs[n_l][k0 + 4];
        uint4 bi;
        bi.x = permsel(v0.y, v0.x, sel);
        bi.y = permsel(v0.w, v0.z, sel);
        bi.z = permsel(v1.y, v1.x, sel);
        bi.w = permsel(v1.w, v1.z, sel);
        half8 bf = __builtin_bit_cast(half8, bi);
        acc = __builtin_amdgcn_mfma_f32_16x16x32_f16(af, bf, acc, 0, 0, 0);
    }

    // D: col=lane&15, row(b-local)=q*4+r [verified]; pair cos/sin via xor(1)
    float aS0 = __shfl_xor(acc[0], 1);
    float aS1 = __shfl_xor(acc[1], 1);
    float aS2 = __shfl_xor(acc[2], 1);
    float aS3 = __shfl_xor(acc[3], 1);
    if (!comp) {
        const float wt_r = OMEGA_ANC * t_ptr[0] * INV_2PI; // anchor phase, revolutions
        float aC[4] = {acc[0], acc[1], acc[2], acc[3]};
        float aS[4] = {aS0, aS1, aS2, aS3};
#pragma unroll
        for (int r = 0; r < 4; ++r) {
            int b = mt * 16 + q * 4 + r;
            float ph = phi[b * N_SZ + n];
            float pr = ph * INV_2PI;                       // [0,1): no reduction
            float ss = vsin_r(pr), cc = vcos_r(pr);
            float anc = vsin_r(vfract(wt_r - pr));         // sin(wt - ph)
            out[b * N_SZ + n] = fmaf(A_ANC, anc, ss * aC[r] - cc * aS[r]);
        }
    }
}

extern "C" void kernel_launch(void* const* d_in, const int* in_sizes, int n_in,
                              void* d_out, int out_size, void* d_ws, size_t ws_size,
                              hipStream_t stream) {
    const float* t   = (const float*)d_in[0];
    const float* phi = (const float*)d_in[1];
    const float* xi  = (const float*)d_in[2];
    float* out = (float*)d_out;

    char* w = (char*)d_ws;
    uint32_t* XPT   = (uint32_t*)w;                        // N*P dwords  = 4 MB
    float* m_total  = (float*)(w + 4u * 1024 * 1024);      // 64*256 f32  = 64 KB

    hipMemsetAsync(m_total, 0, B_SZ * P_SZ * sizeof(float), stream);
    k_mpart_mfma<<<dim3(64, 8), 256, 0, stream>>>(phi, xi, XPT, m_total);
    k_coupling_mfma<<<dim3(4, 128), 256, 0, stream>>>(XPT, m_total, phi, t, out);
}

// Round 2
// 74.970 us; speedup vs baseline: 1.0120x; 1.0120x over previous
//
#include <hip/hip_runtime.h>
#include <hip/hip_fp16.h>
#include <math.h>
#include <stdint.h>

#define B_SZ 64
#define P_SZ 256
#define N_SZ 4096
#define A_ANC 0.08f
#define OMEGA_ANC 1256.6370614359172f
#define INV_2PI 0.15915494309189535f

typedef _Float16 half8 __attribute__((ext_vector_type(8)));
typedef float floatx4 __attribute__((ext_vector_type(4)));

// raw v_sin/v_cos: D = sin(2*pi*r). Inputs pre-scaled by 1/2pi (args in [0,2pi)).
__device__ __forceinline__ float vsin_r(float r) {
#if __has_builtin(__builtin_amdgcn_sinf)
    return __builtin_amdgcn_sinf(r);
#else
    return __sinf(r * 6.283185307179586f);
#endif
}
__device__ __forceinline__ float vcos_r(float r) {
#if __has_builtin(__builtin_amdgcn_cosf)
    return __builtin_amdgcn_cosf(r);
#else
    return __cosf(r * 6.283185307179586f);
#endif
}
__device__ __forceinline__ float vfract(float r) {
#if __has_builtin(__builtin_amdgcn_fractf)
    return __builtin_amdgcn_fractf(r);
#else
    return r - floorf(r);
#endif
}
// {cos(x), sin(x)} packed to half2 dword in one v_cvt_pkrtz
__device__ __forceinline__ uint32_t cs_pack(float x) {
    float r = x * INV_2PI;
    return __builtin_bit_cast(uint32_t,
        __builtin_amdgcn_cvt_pkrtz(vcos_r(r), vsin_r(r)));
}

__device__ __forceinline__ uint32_t permsel(uint32_t hi, uint32_t lo, uint32_t sel) {
#if __has_builtin(__builtin_amdgcn_perm)
    return __builtin_amdgcn_perm(hi, lo, sel);
#else
    unsigned long long v = ((unsigned long long)hi << 32) | lo;
    uint32_t r = 0;
#pragma unroll
    for (int i = 0; i < 4; ++i)
        r |= (uint32_t)((v >> (8 * ((sel >> (8 * i)) & 7))) & 0xff) << (8 * i);
    return r;
#endif
}

// K1: m-GEMM via MFMA (R5-R9 verified math). R10: NO global atomics -- the 4
// waves of a block compute partials for the SAME (bt,pt) tile, so reduce them
// in LDS and emit plain stores to m_part[y][b][p] (8*64*256 f32 = 512 KB).
// This deletes 524K device-scope atomicAdds (32-way collisions on a 64 KB
// region -- the predicted ~20-30 us serialization) and the memset dispatch.
// bt==0 waves store B-frags to XPT[n][p] ({cos,sin} half2 dword), each (n,p) once.
// grid (64, 8) x 4 waves = 2048 waves = 8/CU.
__global__ __launch_bounds__(256) void k_mpart_mfma(const float* __restrict__ phi,
                                                    const float* __restrict__ xi,
                                                    uint32_t* __restrict__ XPT,
                                                    float* __restrict__ m_part) {
    const int bt = blockIdx.x & 3;          // b-tile (4 x 16)
    const int pt = blockIdx.x >> 2;         // p-tile (16 x 16)
    const int w  = threadIdx.x >> 6;
    const int lane = threadIdx.x & 63;
    const int m = lane & 15;
    const int q = lane >> 4;

    const int c  = blockIdx.y * 4 + w;      // K chunk 0..31 (128 n each)
    const int n0 = c * 128;
    const int b_row = bt * 16 + m;
    const int p_row = pt * 16 + m;

    floatx4 acc = {0.f, 0.f, 0.f, 0.f};
#pragma unroll
    for (int s = 0; s < 8; ++s) {
        const int nb = n0 + s * 16 + q * 4;                    // this lane's 4 n's
        float4 ph = *(const float4*)&phi[b_row * N_SZ + nb];   // A source (line-dense)
        float4 xv = *(const float4*)&xi[p_row * N_SZ + nb];    // B source (line-dense)
        uint4 ai, bi;
        ai.x = cs_pack(ph.x); ai.y = cs_pack(ph.y);
        ai.z = cs_pack(ph.z); ai.w = cs_pack(ph.w);
        bi.x = cs_pack(xv.x); bi.y = cs_pack(xv.y);
        bi.z = cs_pack(xv.z); bi.w = cs_pack(xv.w);
        if (bt == 0) {                                         // wave-uniform branch
            XPT[(nb + 0) * P_SZ + p_row] = bi.x;
            XPT[(nb + 1) * P_SZ + p_row] = bi.y;
            XPT[(nb + 2) * P_SZ + p_row] = bi.z;
            XPT[(nb + 3) * P_SZ + p_row] = bi.w;
        }
        half8 af = __builtin_bit_cast(half8, ai);
        half8 bf = __builtin_bit_cast(half8, bi);
        acc = __builtin_amdgcn_mfma_f32_16x16x32_f16(af, bf, acc, 0, 0, 0);
    }

    // D: col(p)=lane&15, row(b)=q*4+r [verified]. Cross-wave reduce in LDS
    // (pad 17 to break the m-bank aliasing), then one plain store per element.
    __shared__ float red[4][16][17];
#pragma unroll
    for (int r = 0; r < 4; ++r) red[w][q * 4 + r][m] = acc[r];
    __syncthreads();
    const int bl = threadIdx.x >> 4;       // 0..15 b-local
    const int pl = threadIdx.x & 15;       // 0..15 p-local
    float sum = red[0][bl][pl] + red[1][bl][pl] + red[2][bl][pl] + red[3][bl][pl];
    m_part[(blockIdx.y * B_SZ + bt * 16 + bl) * P_SZ + pt * 16 + pl] = sum;
}

// K2: in-block softmax + coupling MFMA + anchor (R6-R9 verified math).
// Softmax: wave w computes weight rows bl=w*4..w*4+3 for this block's mt; R10:
// m_total is now 8 y-partials summed inline (8 independent dwordx4 loads,
// L2-resident). B staged through LDS row-dense (R8). One __syncthreads.
// grid (4 mt, 128 ctg) = 512 blocks, ~41KB LDS, 8 waves/CU.
__global__ __launch_bounds__(256) void k_coupling_mfma(const uint32_t* __restrict__ XPT,
                                                       const float* __restrict__ m_part,
                                                       const float* __restrict__ phi,
                                                       const float* __restrict__ t_ptr,
                                                       float* __restrict__ out) {
    const int mt = blockIdx.x;                             // 0..3
    const int ctg = blockIdx.y;                            // 0..127
    const int tid = threadIdx.x;
    const int w = tid >> 6;
    const int lane = tid & 63;
    const int cl = lane & 15;
    const int q  = lane >> 4;

    __shared__ uint32_t xs[32][260];                       // 32 XPT rows + pad
    __shared__ _Float16 wh[16][264];                       // weight rows + pad

    const int n0 = ctg * 32;
#pragma unroll
    for (int it = 0; it < 8; ++it) {
        int i = tid + it * 256;
        int row = i >> 6, seg = i & 63;
        uint4 v = *(const uint4*)&XPT[(n0 + row) * P_SZ + seg * 4];
        *(uint4*)&xs[row][seg * 4] = v;
    }

    // softmax for this block's 16 b-rows; wave w owns bl = w*4..w*4+3
#pragma unroll
    for (int j = 0; j < 4; ++j) {
        const int bl = w * 4 + j;
        float4 v = {0.f, 0.f, 0.f, 0.f};
#pragma unroll
        for (int y = 0; y < 8; ++y) {
            float4 u = *(const float4*)
                &m_part[(y * B_SZ + mt * 16 + bl) * P_SZ + lane * 4];
            v.x += u.x; v.y += u.y; v.z += u.z; v.w += u.w;
        }
        float4 l = {v.x * (1.0f / 4096.0f), v.y * (1.0f / 4096.0f),
                    v.z * (1.0f / 4096.0f), v.w * (1.0f / 4096.0f)};
        float mx = fmaxf(fmaxf(l.x, l.y), fmaxf(l.z, l.w));
        for (int o = 32; o > 0; o >>= 1) mx = fmaxf(mx, __shfl_xor(mx, o));
        float e0 = __expf(l.x - mx), e1 = __expf(l.y - mx);
        float e2 = __expf(l.z - mx), e3 = __expf(l.w - mx);
        float s = e0 + e1 + e2 + e3;
        for (int o = 32; o > 0; o >>= 1) s += __shfl_xor(s, o);
        float rs = 1.0f / s;
        uint2 pk;
        pk.x = __builtin_bit_cast(uint32_t,
                 __builtin_amdgcn_cvt_pkrtz(e0 * rs, e1 * rs));
        pk.y = __builtin_bit_cast(uint32_t,
                 __builtin_amdgcn_cvt_pkrtz(e2 * rs, e3 * rs));
        *(uint2*)&wh[bl][lane * 4] = pk;                   // 8B ds_write
    }
    __syncthreads();

    const int ct  = ctg * 4 + w;
    const int col = ct * 16 + cl;                          // 0..8191
    const int n   = col >> 1;
    const int n_l = w * 8 + (cl >> 1);                     // n - n0
    const int comp = col & 1;                              // 0=cos(lo), 1=sin(hi)
    const uint32_t sel = comp ? 0x07060302u : 0x05040100u;

    floatx4 acc = {0.f, 0.f, 0.f, 0.f};
#pragma unroll
    for (int s = 0; s < 8; ++s) {
        const int k0 = s * 32 + q * 8;                     // this lane's first p
        half8 af = *(const half8*)&wh[cl][k0];             // LDS weight frag
        uint4 v0 = *(const uint4*)&xs[n_l][k0];            // ds_read_b128
        uint4 v1 = *(const uint4*)&xs[n_l][k0 + 4];
        uint4 bi;
        bi.x = permsel(v0.y, v0.x, sel);
        bi.y = permsel(v0.w, v0.z, sel);
        bi.z = permsel(v1.y, v1.x, sel);
        bi.w = permsel(v1.w, v1.z, sel);
        half8 bf = __builtin_bit_cast(half8, bi);
        acc = __builtin_amdgcn_mfma_f32_16x16x32_f16(af, bf, acc, 0, 0, 0);
    }

    // D: col=lane&15, row(b-local)=q*4+r [verified]; pair cos/sin via xor(1)
    float aS0 = __shfl_xor(acc[0], 1);
    float aS1 = __shfl_xor(acc[1], 1);
    float aS2 = __shfl_xor(acc[2], 1);
    float aS3 = __shfl_xor(acc[3], 1);
    if (!comp) {
        const float wt_r = OMEGA_ANC * t_ptr[0] * INV_2PI; // anchor phase, revolutions
        float aC[4] = {acc[0], acc[1], acc[2], acc[3]};
        float aS[4] = {aS0, aS1, aS2, aS3};
#pragma unroll
        for (int r = 0; r < 4; ++r) {
            int b = mt * 16 + q * 4 + r;
            float ph = phi[b * N_SZ + n];
            float pr = ph * INV_2PI;                       // [0,1): no reduction
            float ss = vsin_r(pr), cc = vcos_r(pr);
            float anc = vsin_r(vfract(wt_r - pr));         // sin(wt - ph)
            out[b * N_SZ + n] = fmaf(A_ANC, anc, ss * aC[r] - cc * aS[r]);
        }
    }
}

extern "C" void kernel_launch(void* const* d_in, const int* in_sizes, int n_in,
                              void* d_out, int out_size, void* d_ws, size_t ws_size,
                              hipStream_t stream) {
    const float* t   = (const float*)d_in[0];
    const float* phi = (const float*)d_in[1];
    const float* xi  = (const float*)d_in[2];
    float* out = (float*)d_out;

    char* w = (char*)d_ws;
    uint32_t* XPT  = (uint32_t*)w;                         // N*P dwords  = 4 MB
    float* m_part  = (float*)(w + 4u * 1024 * 1024);       // 8*64*256 f32 = 512 KB

    k_mpart_mfma<<<dim3(64, 8), 256, 0, stream>>>(phi, xi, XPT, m_part);
    k_coupling_mfma<<<dim3(4, 128), 256, 0, stream>>>(XPT, m_part, phi, t, out);
}